// Round 1
// baseline (431.600 us; speedup 1.0000x reference)
//
#include <hip/hip_runtime.h>
#include <math.h>

#define BS 32
#define S  2048
#define H  1024

// ---------------------------------------------------------------------------
// Kernel 1: v[b,h] = sum_k hidden[b,k] * W[k,h]   (v = hidden @ W)
// grid (H/256, BS), block 256. hidden row staged in LDS; W reads coalesced
// across threads (thread t reads column h = bx*256+t of row k).
// ---------------------------------------------------------------------------
__global__ __launch_bounds__(256) void compute_v(const float* __restrict__ hidden,
                                                 const float* __restrict__ W,
                                                 float* __restrict__ v) {
    __shared__ float hid[H];
    const int b   = blockIdx.y;
    const int tid = threadIdx.x;

    // load hidden[b,:] (1024 floats) via float4: 256 threads x 16B
    const float4* hid4 = (const float4*)(hidden + b * H);
    ((float4*)hid)[tid] = hid4[tid];
    __syncthreads();

    const int h = blockIdx.x * 256 + tid;
    float acc = 0.f;
#pragma unroll 8
    for (int k = 0; k < H; ++k) {
        acc = fmaf(W[k * H + h], hid[k], acc);
    }
    v[b * H + h] = acc;
}

// ---------------------------------------------------------------------------
// Kernel 2: scores[b,s] = dot(enc[b,s,:], v[b,:])
// grid (S/64, BS), block 256 (4 waves), 16 s-rows per wave.
// v[b,:] preloaded into 16 registers/lane (float4 x 4); enc read with
// perfectly coalesced float4 (wave covers 1 KiB per load instruction).
// Bias is omitted: it is constant per softmax row and cancels.
// scores are written directly into d_out (same size: BS*S floats).
// ---------------------------------------------------------------------------
__global__ __launch_bounds__(256) void compute_scores(const float* __restrict__ enc,
                                                      const float* __restrict__ v,
                                                      float* __restrict__ scores) {
    const int b    = blockIdx.y;
    const int tid  = threadIdx.x;
    const int wave = tid >> 6;
    const int lane = tid & 63;

    // preload v[b,:] fragment: lane holds v[it*256 + lane*4 .. +3], it=0..3
    const float4* v4 = (const float4*)(v + b * H);
    float4 vr[4];
#pragma unroll
    for (int it = 0; it < 4; ++it) vr[it] = v4[it * 64 + lane];

    const int s0 = blockIdx.x * 64 + wave * 16;
    const float4* encb = (const float4*)enc + (size_t)b * S * (H / 4);

#pragma unroll 2
    for (int i = 0; i < 16; ++i) {
        const int s = s0 + i;
        const float4* e4 = encb + (size_t)s * (H / 4);
        float acc = 0.f;
#pragma unroll
        for (int it = 0; it < 4; ++it) {
            float4 e = e4[it * 64 + lane];
            acc = fmaf(e.x, vr[it].x, acc);
            acc = fmaf(e.y, vr[it].y, acc);
            acc = fmaf(e.z, vr[it].z, acc);
            acc = fmaf(e.w, vr[it].w, acc);
        }
        // wave (64-lane) reduction
#pragma unroll
        for (int off = 32; off > 0; off >>= 1)
            acc += __shfl_down(acc, off, 64);
        if (lane == 0) scores[b * S + s] = acc;
    }
}

// ---------------------------------------------------------------------------
// Kernel 3: in-place row softmax on scores (= d_out). grid BS, block 256,
// 8 elements/thread. Block-wide max then sum via shuffle + LDS.
// ---------------------------------------------------------------------------
__global__ __launch_bounds__(256) void softmax_rows(float* __restrict__ scores) {
    const int b    = blockIdx.x;
    const int tid  = threadIdx.x;
    const int wave = tid >> 6;
    const int lane = tid & 63;
    __shared__ float red[4];

    float x[8];
    float m = -INFINITY;
#pragma unroll
    for (int i = 0; i < 8; ++i) {
        x[i] = scores[b * S + tid + i * 256];
        m = fmaxf(m, x[i]);
    }
#pragma unroll
    for (int off = 1; off < 64; off <<= 1)
        m = fmaxf(m, __shfl_xor(m, off, 64));
    if (lane == 0) red[wave] = m;
    __syncthreads();
    m = fmaxf(fmaxf(red[0], red[1]), fmaxf(red[2], red[3]));

    float sum = 0.f;
#pragma unroll
    for (int i = 0; i < 8; ++i) {
        x[i] = __expf(x[i] - m);
        sum += x[i];
    }
#pragma unroll
    for (int off = 1; off < 64; off <<= 1)
        sum += __shfl_xor(sum, off, 64);
    __syncthreads();   // red[] reuse
    if (lane == 0) red[wave] = sum;
    __syncthreads();
    sum = (red[0] + red[1]) + (red[2] + red[3]);
    const float inv = 1.0f / sum;

#pragma unroll
    for (int i = 0; i < 8; ++i)
        scores[b * S + tid + i * 256] = x[i] * inv;
}

extern "C" void kernel_launch(void* const* d_in, const int* in_sizes, int n_in,
                              void* d_out, int out_size, void* d_ws, size_t ws_size,
                              hipStream_t stream) {
    const float* hidden = (const float*)d_in[0];   // [BS, H]
    const float* enc    = (const float*)d_in[1];   // [BS, S, H]
    const float* W      = (const float*)d_in[2];   // [H, H]
    // d_in[3] = bias: unused — cancels in the softmax.

    float* v      = (float*)d_ws;    // BS*H floats = 128 KiB scratch
    float* outp   = (float*)d_out;   // BS*S floats; scores then softmax in place

    dim3 g1(H / 256, BS);
    compute_v<<<g1, 256, 0, stream>>>(hidden, W, v);

    dim3 g2(S / 64, BS);
    compute_scores<<<g2, 256, 0, stream>>>(enc, v, outp);

    softmax_rows<<<BS, 256, 0, stream>>>(outp);
}

// Round 3
// 358.727 us; speedup vs baseline: 1.2031x; 1.2031x over previous
//
#include <hip/hip_runtime.h>
#include <math.h>

#define BS 32
#define S  2048
#define H  1024

// native clang vector type — required for __builtin_nontemporal_load
typedef float vfloat4 __attribute__((ext_vector_type(4)));

// ---------------------------------------------------------------------------
// Kernel 1: v[b,h] = sum_k hidden[b,k] * W[k,h]   (v = hidden @ W)
// grid (H/64, BS) = 512 blocks, block 256 = 4 waves.
// Split-k across waves: wave w accumulates k in [w*256, w*256+256) for the
// 64 columns h = bx*64 + lane; LDS combine. 2 blocks/CU, dependent-FMA chain
// length 256 instead of 1024.
// ---------------------------------------------------------------------------
__global__ __launch_bounds__(256) void compute_v(const float* __restrict__ hidden,
                                                 const float* __restrict__ W,
                                                 float* __restrict__ v) {
    __shared__ float hid[H];
    __shared__ float part[4][64];
    const int b    = blockIdx.y;
    const int tid  = threadIdx.x;
    const int wave = tid >> 6;
    const int lane = tid & 63;

    // stage hidden[b,:] : 256 threads x float4 = 1024 floats
    ((float4*)hid)[tid] = ((const float4*)(hidden + b * H))[tid];
    __syncthreads();

    const int h = blockIdx.x * 64 + lane;
    const float* Wp = W + (size_t)(wave * 256) * H + h;
    const float* hp = hid + wave * 256;
    float acc = 0.f;
#pragma unroll 8
    for (int k = 0; k < 256; ++k)
        acc = fmaf(Wp[(size_t)k * H], hp[k], acc);

    part[wave][lane] = acc;
    __syncthreads();
    if (wave == 0) {
        float r = (part[0][lane] + part[1][lane]) + (part[2][lane] + part[3][lane]);
        v[b * H + h] = r;
    }
}

// ---------------------------------------------------------------------------
// Kernel 2: scores[b,s] = dot(enc[b,s,:], v[b,:])
// grid (S/64, BS) = 1024 blocks, block 256 (4 waves), 16 rows/wave processed
// in groups of 4 so four shuffle-reduction chains pipeline. enc loads are
// perfectly coalesced float4 (1 KiB per wave per instruction), nontemporal
// (streamed exactly once). v[b,:] held in 16 regs/lane.
// Bias omitted: constant per softmax row, cancels.
// ---------------------------------------------------------------------------
__global__ __launch_bounds__(256) void compute_scores(const float* __restrict__ enc,
                                                      const float* __restrict__ v,
                                                      float* __restrict__ scores) {
    const int b    = blockIdx.y;
    const int tid  = threadIdx.x;
    const int wave = tid >> 6;
    const int lane = tid & 63;

    const float4* v4 = (const float4*)(v + b * H);
    float4 vr[4];
#pragma unroll
    for (int it = 0; it < 4; ++it) vr[it] = v4[it * 64 + lane];

    const int s0 = blockIdx.x * 64 + wave * 16;
    const vfloat4* encb = (const vfloat4*)enc + (size_t)b * S * (H / 4);

#pragma unroll
    for (int i = 0; i < 16; i += 4) {
        float acc[4] = {0.f, 0.f, 0.f, 0.f};
#pragma unroll
        for (int j = 0; j < 4; ++j) {
            const vfloat4* e4 = encb + (size_t)(s0 + i + j) * (H / 4);
#pragma unroll
            for (int it = 0; it < 4; ++it) {
                vfloat4 e = __builtin_nontemporal_load(&e4[it * 64 + lane]);
                acc[j] = fmaf(e.x, vr[it].x, acc[j]);
                acc[j] = fmaf(e.y, vr[it].y, acc[j]);
                acc[j] = fmaf(e.z, vr[it].z, acc[j]);
                acc[j] = fmaf(e.w, vr[it].w, acc[j]);
            }
        }
        // four independent 64-lane butterfly reductions — chains pipeline
#pragma unroll
        for (int off = 32; off > 0; off >>= 1) {
#pragma unroll
            for (int j = 0; j < 4; ++j)
                acc[j] += __shfl_xor(acc[j], off, 64);
        }
        if (lane < 4)
            scores[b * S + s0 + i + lane] = acc[lane];  // acc[j] valid in all lanes after xor
    }
}

// ---------------------------------------------------------------------------
// Kernel 3: in-place row softmax on scores (= d_out). grid BS, block 256,
// 8 elements/thread.
// ---------------------------------------------------------------------------
__global__ __launch_bounds__(256) void softmax_rows(float* __restrict__ scores) {
    const int b    = blockIdx.x;
    const int tid  = threadIdx.x;
    const int wave = tid >> 6;
    const int lane = tid & 63;
    __shared__ float red[4];

    float x[8];
    float m = -INFINITY;
#pragma unroll
    for (int i = 0; i < 8; ++i) {
        x[i] = scores[b * S + tid + i * 256];
        m = fmaxf(m, x[i]);
    }
#pragma unroll
    for (int off = 1; off < 64; off <<= 1)
        m = fmaxf(m, __shfl_xor(m, off, 64));
    if (lane == 0) red[wave] = m;
    __syncthreads();
    m = fmaxf(fmaxf(red[0], red[1]), fmaxf(red[2], red[3]));

    float sum = 0.f;
#pragma unroll
    for (int i = 0; i < 8; ++i) {
        x[i] = __expf(x[i] - m);
        sum += x[i];
    }
#pragma unroll
    for (int off = 1; off < 64; off <<= 1)
        sum += __shfl_xor(sum, off, 64);
    __syncthreads();   // red[] reuse
    if (lane == 0) red[wave] = sum;
    __syncthreads();
    sum = (red[0] + red[1]) + (red[2] + red[3]);
    const float inv = 1.0f / sum;

#pragma unroll
    for (int i = 0; i < 8; ++i)
        scores[b * S + tid + i * 256] = x[i] * inv;
}

extern "C" void kernel_launch(void* const* d_in, const int* in_sizes, int n_in,
                              void* d_out, int out_size, void* d_ws, size_t ws_size,
                              hipStream_t stream) {
    const float* hidden = (const float*)d_in[0];   // [BS, H]
    const float* enc    = (const float*)d_in[1];   // [BS, S, H]
    const float* W      = (const float*)d_in[2];   // [H, H]
    // d_in[3] = bias: unused — cancels in the softmax.

    float* v    = (float*)d_ws;    // BS*H floats = 128 KiB scratch
    float* outp = (float*)d_out;   // BS*S floats; scores then softmax in place

    dim3 g1(H / 64, BS);
    compute_v<<<g1, 256, 0, stream>>>(hidden, W, v);

    dim3 g2(S / 64, BS);
    compute_scores<<<g2, 256, 0, stream>>>(enc, v, outp);

    softmax_rows<<<BS, 256, 0, stream>>>(outp);
}